// Round 3
// baseline (310.335 us; speedup 1.0000x reference)
//
#include <hip/hip_runtime.h>
#include <hip/hip_bf16.h>

typedef __attribute__((ext_vector_type(8))) short s8v;    // 8 bf16
typedef __attribute__((ext_vector_type(4))) short s4v;    // 4 bf16
typedef __attribute__((ext_vector_type(4))) float f4v;    // 4 fp32

__device__ __forceinline__ void g2lds16(const void* g, void* l) {
  __builtin_amdgcn_global_load_lds(
      (__attribute__((address_space(1))) void*)(g),
      (__attribute__((address_space(3))) void*)(l), 16, 0, 0);
}

__device__ __forceinline__ short f2bf(float f) {
  __hip_bfloat16 h = __float2bfloat16(f);
  return *reinterpret_cast<short*>(&h);
}

// ---------------- K0a: x fp32 -> bf16 ----------------
__global__ void k_cvt_x(const float* __restrict__ x, __hip_bfloat16* __restrict__ xb) {
  int i = (blockIdx.x * 256 + threadIdx.x) * 4;
  float4 v = *(const float4*)(x + i);
  __hip_bfloat16 o[4] = {__float2bfloat16(v.x), __float2bfloat16(v.y),
                         __float2bfloat16(v.z), __float2bfloat16(v.w)};
  *(uint2*)(xb + i) = *(const uint2*)(o);
}

// ---------------- K0b: W [1024,3072] fp32 -> Wt [3072,1024] bf16 ----------------
__global__ void k_transpose_w(const float* __restrict__ W, __hip_bfloat16* __restrict__ Wt) {
  __shared__ float tile[32][33];
  int c0 = blockIdx.x * 32;   // over 3072
  int r0 = blockIdx.y * 32;   // over 1024
  int tr = threadIdx.x >> 5;  // 0..7
  int tc = threadIdx.x & 31;
#pragma unroll
  for (int i = 0; i < 32; i += 8)
    tile[tr + i][tc] = W[(size_t)(r0 + tr + i) * 3072 + c0 + tc];
  __syncthreads();
#pragma unroll
  for (int i = 0; i < 32; i += 8)
    Wt[(size_t)(c0 + tr + i) * 1024 + r0 + tc] = __float2bfloat16(tile[tc][tr + i]);
}

// ---------------- K1: GEMM  Y[4096,3072] = A[4096,1024] @ Wt^T, + bias, bf16 out ----
__global__ __launch_bounds__(256) void k_gemm(const __hip_bfloat16* __restrict__ A,
                                              const __hip_bfloat16* __restrict__ Bt,
                                              const float* __restrict__ bias,
                                              __hip_bfloat16* __restrict__ Y) {
  __shared__ __align__(16) __hip_bfloat16 As[128 * 32];
  __shared__ __align__(16) __hip_bfloat16 Bs[128 * 32];
  const int tid = threadIdx.x;
  const int lane = tid & 63, wave = tid >> 6;
  const int m0 = blockIdx.y * 128, n0 = blockIdx.x * 128;
  const int wm = (wave & 1) * 64, wn = (wave >> 1) * 64;
  const int lrow = lane & 15, lk = (lane >> 4) * 8;

  f4v acc[4][4] = {};

  for (int k0 = 0; k0 < 1024; k0 += 32) {
#pragma unroll
    for (int c = 0; c < 2; ++c) {
      int e = c * 2048 + tid * 8;
      int row = e >> 5, col = e & 31;
      g2lds16(A + (size_t)(m0 + row) * 1024 + k0 + col, As + e);
      g2lds16(Bt + (size_t)(n0 + row) * 1024 + k0 + col, Bs + e);
    }
    __syncthreads();
    s8v af[4], bfr[4];
#pragma unroll
    for (int mi = 0; mi < 4; ++mi) af[mi] = *(const s8v*)(As + (wm + mi * 16 + lrow) * 32 + lk);
#pragma unroll
    for (int ni = 0; ni < 4; ++ni) bfr[ni] = *(const s8v*)(Bs + (wn + ni * 16 + lrow) * 32 + lk);
#pragma unroll
    for (int mi = 0; mi < 4; ++mi)
#pragma unroll
      for (int ni = 0; ni < 4; ++ni)
        acc[mi][ni] = __builtin_amdgcn_mfma_f32_16x16x32_bf16(af[mi], bfr[ni], acc[mi][ni], 0, 0, 0);
    __syncthreads();
  }

#pragma unroll
  for (int mi = 0; mi < 4; ++mi) {
    int r = m0 + wm + mi * 16 + (lane >> 4) * 4;
#pragma unroll
    for (int ni = 0; ni < 4; ++ni) {
      int c = n0 + wn + ni * 16 + lrow;
      float bv = bias[c];
#pragma unroll
      for (int reg = 0; reg < 4; ++reg)
        Y[(size_t)(r + reg) * 3072 + c] = __float2bfloat16(acc[mi][ni][reg] + bv);
    }
  }
}

// ---------------- K2: gather y -> Q [b,h,t,d], K [b,h,t,d], Vt [b,h,d,t] ----------
__global__ void k_gather(const __hip_bfloat16* __restrict__ y,
                         __hip_bfloat16* __restrict__ Q,
                         __hip_bfloat16* __restrict__ K,
                         __hip_bfloat16* __restrict__ Vt) {
  __shared__ __align__(16) __hip_bfloat16 lds[16 * 1028];  // rows padded 1024->1028
  int bx = blockIdx.x;
  int s = bx >> 8, rem = bx & 255, b = rem >> 7, tc = rem & 127;
  const __hip_bfloat16* src = y + (size_t)s * 4194304 + (size_t)b * 2097152 + (size_t)tc * 16384;
  for (int c = threadIdx.x; c < 4096; c += 256) {  // 4-bf16 (8B) chunks
    int tt = c >> 8, jc = c & 255;
    *(uint2*)(lds + tt * 1028 + jc * 4) = *(const uint2*)(src + tt * 1024 + jc * 4);
  }
  __syncthreads();
  size_t hb = (size_t)b * 16 * 131072;
  if (s < 2) {
    __hip_bfloat16* dst = (s == 0) ? Q : K;
    for (int e = threadIdx.x; e < 16384; e += 256) {
      int h = e >> 10, r = e & 1023;
      int tt = r >> 6, d = r & 63;
      dst[hb + (size_t)h * 131072 + (size_t)(tc * 16 + tt) * 64 + d] = lds[tt * 1028 + d * 16 + h];
    }
  } else {
    for (int e = threadIdx.x; e < 16384; e += 256) {
      int h = e >> 10, r = e & 1023;
      int d = r >> 4, tt = r & 15;
      Vt[hb + (size_t)h * 131072 + (size_t)d * 2048 + tc * 16 + tt] = lds[tt * 1028 + d * 16 + h];
    }
  }
}

// ---------------- K3: causal flash attention, S^T form, 16 Q rows per wave ----------
// One wave per block. XCD-affine: bh pinned to XCD (bid&7) so K/V (2MB per 4 bh)
// stay L2-resident. S^T = MFMA(A=K, B=Q) -> softmax is per-lane over regs + 2 shfl.
// P (C-layout, k=quad*4+reg) feeds PV (O^T = V^T P^T) directly as the B operand of
// mfma_f32_16x16x16bf16_1k. No __syncthreads in the KV loop.
__global__ __launch_bounds__(64, 3) void k_attn(const __hip_bfloat16* __restrict__ Q,
                                                const __hip_bfloat16* __restrict__ K,
                                                const __hip_bfloat16* __restrict__ Vt,
                                                float* __restrict__ out) {
  __shared__ float Osh[16 * 66];
  const int lane = threadIdx.x;
  const int l = lane & 15, q = lane >> 4;
  const int bid = blockIdx.x;          // 4096 blocks
  const int xcd = bid & 7;             // round-robin XCD assumption (perf-only)
  const int idx = bid >> 3;            // 0..511
  const int bh = xcd + 8 * (idx & 3);  // 4 bh per XCD -> 2MB K+V working set
  const int q16 = 127 - (idx >> 2);    // heavy blocks first
  const int jl = q16 >> 2;             // last KV tile (64-wide)

  const __hip_bfloat16* Kp = K + (size_t)bh * 131072;
  const __hip_bfloat16* Vp = Vt + (size_t)bh * 131072;
  const __hip_bfloat16* Qp = Q + (size_t)bh * 131072 + (size_t)q16 * 1024;

  // Q B-fragment (16 rows, load once): B[n=t][k], t = q16*16 + l, k = kh*32 + q*8 ..
  s8v Qf[2];
#pragma unroll
  for (int kh = 0; kh < 2; ++kh)
    Qf[kh] = *(const s8v*)(Qp + (size_t)l * 64 + kh * 32 + q * 8);

  f4v O[4] = {};
  float m = -INFINITY, lsum = 0.f;
  const float c1 = 0.125f * 1.44269504088896f;  // scale * log2(e)

  auto loadK = [&](int j, s8v(&KF)[4][2]) {
#pragma unroll
    for (int nt = 0; nt < 4; ++nt)
#pragma unroll
      for (int kh = 0; kh < 2; ++kh)
        KF[nt][kh] = *(const s8v*)(Kp + (size_t)j * 4096 + (nt * 16 + l) * 64 + kh * 32 + q * 8);
  };

  auto step = [&](int j, s8v(&KC)[4][2], s8v(&KN)[4][2]) {
    // V fragments: A[m=d][k=s], d = dt*16+l, s = sc*16 + q*4 ..
    s4v Vf[4][4];
#pragma unroll
    for (int sc = 0; sc < 4; ++sc)
#pragma unroll
      for (int dt = 0; dt < 4; ++dt)
        Vf[sc][dt] = *(const s4v*)(Vp + (size_t)(dt * 16 + l) * 2048 + j * 64 + sc * 16 + q * 4);
    int jn = (j + 1 <= jl) ? j + 1 : jl;
    loadK(jn, KN);
    const bool diag = (j == jl);

    f4v S[4];
#pragma unroll
    for (int nt = 0; nt < 4; ++nt) {
      f4v z = {0.f, 0.f, 0.f, 0.f};
      z = __builtin_amdgcn_mfma_f32_16x16x32_bf16(KC[nt][0], Qf[0], z, 0, 0, 0);
      z = __builtin_amdgcn_mfma_f32_16x16x32_bf16(KC[nt][1], Qf[1], z, 0, 0, 0);
      S[nt] = z;
    }
    float p2[4][4];
#pragma unroll
    for (int nt = 0; nt < 4; ++nt)
#pragma unroll
      for (int r = 0; r < 4; ++r) p2[nt][r] = S[nt][r] * c1;
    if (diag) {
      int tg = q16 * 16 + l;
#pragma unroll
      for (int nt = 0; nt < 4; ++nt)
#pragma unroll
        for (int r = 0; r < 4; ++r)
          if (j * 64 + nt * 16 + q * 4 + r > tg) p2[nt][r] = -1e30f;
    }
    float mx = p2[0][0];
#pragma unroll
    for (int nt = 0; nt < 4; ++nt)
#pragma unroll
      for (int r = 0; r < 4; ++r) mx = fmaxf(mx, p2[nt][r]);
    mx = fmaxf(mx, __shfl_xor(mx, 16));
    mx = fmaxf(mx, __shfl_xor(mx, 32));
    float mn = fmaxf(m, mx);
    float alpha = exp2f(m - mn);
    m = mn;
    float rs = 0.f;
    s4v Pf[4];
#pragma unroll
    for (int nt = 0; nt < 4; ++nt)
#pragma unroll
      for (int r = 0; r < 4; ++r) {
        float e = exp2f(p2[nt][r] - mn);
        rs += e;
        Pf[nt][r] = f2bf(e);
      }
    rs += __shfl_xor(rs, 16);
    rs += __shfl_xor(rs, 32);
    lsum = lsum * alpha + rs;
#pragma unroll
    for (int dt = 0; dt < 4; ++dt) O[dt] *= alpha;
#pragma unroll
    for (int sc = 0; sc < 4; ++sc)
#pragma unroll
      for (int dt = 0; dt < 4; ++dt)
        O[dt] = __builtin_amdgcn_mfma_f32_16x16x16bf16_1k(Vf[sc][dt], Pf[sc], O[dt], 0, 0, 0);
  };

  s8v Ka[4][2], Kb[4][2];
  loadK(0, Ka);
  for (int j = 0; j <= jl; j += 2) {
    step(j, Ka, Kb);
    if (j + 1 <= jl) step(j + 1, Kb, Ka);
  }

  // epilogue: O^T -> LDS transpose -> coalesced fp32 stores
  float inv = 1.f / lsum;
#pragma unroll
  for (int dt = 0; dt < 4; ++dt)
#pragma unroll
    for (int r = 0; r < 4; ++r)
      Osh[l * 66 + dt * 16 + q * 4 + r] = O[dt][r] * inv;
  __syncthreads();
  int b = bh >> 4, h = bh & 15;
  float* ob = out + ((size_t)b * 2048 + (size_t)q16 * 16) * 1024 + h * 64;
  int r0 = lane >> 2, c0 = (lane & 3) * 4;
#pragma unroll
  for (int i = 0; i < 4; ++i)
    *(float4*)&ob[(size_t)r0 * 1024 + c0 + i * 16] = *(float4*)&Osh[r0 * 66 + c0 + i * 16];
}

extern "C" void kernel_launch(void* const* d_in, const int* in_sizes, int n_in,
                              void* d_out, int out_size, void* d_ws, size_t ws_size,
                              hipStream_t stream) {
  const float* x = (const float*)d_in[0];     // [2,2048,1024]
  const float* W = (const float*)d_in[1];     // [1024,3072]
  const float* bias = (const float*)d_in[2];  // [3072]
  float* out = (float*)d_out;                 // [2,2048,1024]

  char* ws = (char*)d_ws;
  __hip_bfloat16* xb = (__hip_bfloat16*)ws;                           // 8,388,608 B
  __hip_bfloat16* Wt = (__hip_bfloat16*)(ws + 8388608);               // 6,291,456 B
  __hip_bfloat16* y  = (__hip_bfloat16*)(ws + 8388608 + 6291456);     // 25,165,824 B
  __hip_bfloat16* Qg = (__hip_bfloat16*)(ws + 39845888);              // 8,388,608 B
  __hip_bfloat16* Kg = (__hip_bfloat16*)(ws + 48234496);              // 8,388,608 B
  __hip_bfloat16* Vt = (__hip_bfloat16*)(ws + 56623104);              // 8,388,608 B

  k_cvt_x<<<4096, 256, 0, stream>>>(x, xb);
  k_transpose_w<<<dim3(96, 32), 256, 0, stream>>>(W, Wt);
  k_gemm<<<dim3(24, 32), 256, 0, stream>>>(xb, Wt, bias, y);
  k_gather<<<768, 256, 0, stream>>>(y, Qg, Kg, Vt);
  k_attn<<<4096, 64, 0, stream>>>(Qg, Kg, Vt, out);
}

// Round 5
// 196.353 us; speedup vs baseline: 1.5805x; 1.5805x over previous
//
#include <hip/hip_runtime.h>
#include <hip/hip_bf16.h>

typedef __attribute__((ext_vector_type(8))) short s8v;    // 8 bf16
typedef __attribute__((ext_vector_type(4))) short s4v;    // 4 bf16
typedef __attribute__((ext_vector_type(4))) float f4v;    // 4 fp32

__device__ __forceinline__ void g2lds16(const void* g, void* l) {
  __builtin_amdgcn_global_load_lds(
      (__attribute__((address_space(1))) void*)(g),
      (__attribute__((address_space(3))) void*)(l), 16, 0, 0);
}

__device__ __forceinline__ short f2bf(float f) {
  __hip_bfloat16 h = __float2bfloat16(f);
  return *reinterpret_cast<short*>(&h);
}

// ---------------- K0: fused x->bf16 cvt  +  W transpose->bf16 ----------------
__global__ void k_prep(const float* __restrict__ x, const float* __restrict__ W,
                       __hip_bfloat16* __restrict__ xb, __hip_bfloat16* __restrict__ Wt) {
  int bx = blockIdx.x;
  if (bx < 4096) {
    int i = (bx * 256 + threadIdx.x) * 4;
    float4 v = *(const float4*)(x + i);
    __hip_bfloat16 o[4] = {__float2bfloat16(v.x), __float2bfloat16(v.y),
                           __float2bfloat16(v.z), __float2bfloat16(v.w)};
    *(uint2*)(xb + i) = *(const uint2*)(o);
  } else {
    __shared__ float tile[32][33];
    int r = bx - 4096;            // 0..3071 = 32 x 96
    int rt = r / 96;              // over 1024/32
    int ct = r - rt * 96;         // over 3072/32
    int c0 = ct * 32, r0 = rt * 32;
    int tr = threadIdx.x >> 5, tc = threadIdx.x & 31;
#pragma unroll
    for (int i = 0; i < 32; i += 8)
      tile[tr + i][tc] = W[(size_t)(r0 + tr + i) * 3072 + c0 + tc];
    __syncthreads();
#pragma unroll
    for (int i = 0; i < 32; i += 8)
      Wt[(size_t)(c0 + tr + i) * 1024 + r0 + tc] = __float2bfloat16(tile[tc][tr + i]);
  }
}

// ---------------- K1: GEMM + fused QKV scatter epilogue ----------------
// Y element (row rr, col c): flat = rr*3072 + c. With u = 3*rr + (c>>10):
//   s = u>>12, b = (u>>11)&1, t = u&2047, d = (c&1023)>>4, h = c&15.
// s=0 -> Q[b,h,t,d], s=1 -> K[b,h,t,d], s=2 -> Vt[b,h,d,t]
__global__ __launch_bounds__(256) void k_gemm(const __hip_bfloat16* __restrict__ A,
                                              const __hip_bfloat16* __restrict__ Bt,
                                              const float* __restrict__ bias,
                                              __hip_bfloat16* __restrict__ Q,
                                              __hip_bfloat16* __restrict__ K,
                                              __hip_bfloat16* __restrict__ Vt) {
  __shared__ __align__(16) __hip_bfloat16 As[128 * 32];
  __shared__ __align__(16) __hip_bfloat16 Bs[128 * 32];
  const int tid = threadIdx.x;
  const int lane = tid & 63, wave = tid >> 6;
  const int m0 = blockIdx.y * 128, n0 = blockIdx.x * 128;
  const int wm = (wave & 1) * 64, wn = (wave >> 1) * 64;
  const int lrow = lane & 15, lk = (lane >> 4) * 8;
  const int quad = lane >> 4;

  f4v acc[4][4] = {};

  for (int k0 = 0; k0 < 1024; k0 += 32) {
#pragma unroll
    for (int c = 0; c < 2; ++c) {
      int e = c * 2048 + tid * 8;
      int row = e >> 5, col = e & 31;
      g2lds16(A + (size_t)(m0 + row) * 1024 + k0 + col, As + e);
      g2lds16(Bt + (size_t)(n0 + row) * 1024 + k0 + col, Bs + e);
    }
    __syncthreads();
    s8v af[4], bfr[4];
#pragma unroll
    for (int mi = 0; mi < 4; ++mi) af[mi] = *(const s8v*)(As + (wm + mi * 16 + lrow) * 32 + lk);
#pragma unroll
    for (int ni = 0; ni < 4; ++ni) bfr[ni] = *(const s8v*)(Bs + (wn + ni * 16 + lrow) * 32 + lk);
#pragma unroll
    for (int mi = 0; mi < 4; ++mi)
#pragma unroll
      for (int ni = 0; ni < 4; ++ni)
        acc[mi][ni] = __builtin_amdgcn_mfma_f32_16x16x32_bf16(af[mi], bfr[ni], acc[mi][ni], 0, 0, 0);
    __syncthreads();
  }

  // epilogue: per-row destination decode, d-packed 8B stores for Q/K
  const int cw = n0 + wn;            // multiple of 64 -> c10 wave-uniform
  const int c10 = cw >> 10;          // 0..2
  const int d0 = (cw & 1023) >> 4;   // multiple of 4
  const int h = lrow;
  float bv[4];
#pragma unroll
  for (int ni = 0; ni < 4; ++ni) bv[ni] = bias[cw + ni * 16 + lrow];

#pragma unroll
  for (int mi = 0; mi < 4; ++mi) {
    int rbase = m0 + wm + mi * 16 + quad * 4;
#pragma unroll
    for (int reg = 0; reg < 4; ++reg) {
      int rr = rbase + reg;
      int u = 3 * rr + c10;
      int s = u >> 12;
      int b = (u >> 11) & 1;
      int t = u & 2047;
      if (s < 2) {
        __hip_bfloat16* dst = (s == 0) ? Q : K;
        s4v pk;
#pragma unroll
        for (int ni = 0; ni < 4; ++ni) pk[ni] = f2bf(acc[mi][ni][reg] + bv[ni]);
        *(s4v*)(dst + ((size_t)(b * 16 + h) * 2048 + t) * 64 + d0) = pk;
      } else {
#pragma unroll
        for (int ni = 0; ni < 4; ++ni)
          Vt[((size_t)(b * 16 + h) * 64 + d0 + ni) * 2048 + t] =
              __float2bfloat16(acc[mi][ni][reg] + bv[ni]);
      }
    }
  }
}

// ---------------- K2: causal flash attention ----------------
// 4 waves / block, 64 Q rows (16/wave). K/V tiles staged coalesced via
// global_load_lds into a double-buffered, XOR-swizzled LDS (swizzle applied by
// permuting the *global source* per lane). One barrier per KV tile.
// S^T = MFMA(A=K, B=Q): softmax per-lane over regs + 2 shuffles; P stays in
// registers and feeds PV (O^T = V^T P^T) as the B operand of 16x16x16bf16_1k.
__global__ __launch_bounds__(256, 3) void k_attn(const __hip_bfloat16* __restrict__ Q,
                                                 const __hip_bfloat16* __restrict__ K,
                                                 const __hip_bfloat16* __restrict__ Vt,
                                                 float* __restrict__ out) {
  __shared__ __align__(16) char lds[2][16384];  // per buf: K tile 8KB | V tile 8KB

  const int tid = threadIdx.x;
  const int lane = tid & 63, w = tid >> 6;
  const int l = lane & 15, q = lane >> 4, lx = l & 7;

  const int bid = blockIdx.x;           // 1024 blocks
  const int xcd = bid & 7;
  const int idx = bid >> 3;             // 0..127
  const int bh = xcd + 8 * (idx & 3);   // 4 bh per XCD -> 2MB K+V in its L2
  const int qb = 31 - (idx >> 2);       // heavy blocks first; tiles 0..qb

  const char* Kb = (const char*)(K + (size_t)bh * 131072);
  const char* Vb = (const char*)(Vt + (size_t)bh * 131072);
  const __hip_bfloat16* Qp = Q + (size_t)bh * 131072 + (size_t)qb * 4096;

  // Q fragment (load once): B[n=t][k], t = qb*64 + w*16 + l
  s8v Qf[2];
#pragma unroll
  for (int kh = 0; kh < 2; ++kh)
    Qf[kh] = *(const s8v*)(Qp + (size_t)(w * 16 + l) * 64 + kh * 32 + q * 8);

  f4v O[4] = {};
  float m = -INFINITY, lsum = 0.f;
  const float c1 = 0.125f * 1.44269504088896f;  // scale * log2(e)
  const int tg = qb * 64 + w * 16 + l;          // this lane's global Q row

  auto stage = [&](int j, char* buf) {
#pragma unroll
    for (int c = 0; c < 4; ++c) {
      int chunk = w * 4 + c;            // 0..15
      int ls = chunk * 64 + lane;       // 16B-slot index
      if (chunk < 8) {                  // K tile: LDS[row][kb] = K[row][kb ^ (row&7)]
        int row = ls >> 3, kb = ls & 7;
        g2lds16(Kb + (size_t)j * 8192 + row * 128 + ((kb ^ (row & 7)) << 4),
                buf + ls * 16);
      } else {                          // V tile: LDS[d][kb] = V^T[d][kb ^ (d&7)]
        int ls2 = ls - 512;
        int d = ls2 >> 3, kb = ls2 & 7;
        g2lds16(Vb + (size_t)d * 4096 + (size_t)j * 128 + ((kb ^ (d & 7)) << 4),
                buf + 8192 + ls2 * 16);
      }
    }
  };

  stage(0, lds[0]);
  __syncthreads();

  for (int j = 0; j <= qb; ++j) {
    const char* Kl = lds[j & 1];
    const char* Vl = Kl + 8192;
    if (j < qb) stage(j + 1, lds[(j + 1) & 1]);

    // S^T: A = K rows (m = s_local), B = Q (n = t)
    f4v S[4];
#pragma unroll
    for (int nt = 0; nt < 4; ++nt) {
      const char* rowp = Kl + (nt * 16 + l) * 128;
      s8v k0 = *(const s8v*)(rowp + ((q ^ lx) << 4));
      s8v k1 = *(const s8v*)(rowp + (((4 + q) ^ lx) << 4));
      f4v z = {0.f, 0.f, 0.f, 0.f};
      z = __builtin_amdgcn_mfma_f32_16x16x32_bf16(k0, Qf[0], z, 0, 0, 0);
      z = __builtin_amdgcn_mfma_f32_16x16x32_bf16(k1, Qf[1], z, 0, 0, 0);
      S[nt] = z;
    }

    float p2[4][4];
#pragma unroll
    for (int nt = 0; nt < 4; ++nt)
#pragma unroll
      for (int r = 0; r < 4; ++r) p2[nt][r] = S[nt][r] * c1;
    if (j == qb) {
#pragma unroll
      for (int nt = 0; nt < 4; ++nt)
#pragma unroll
        for (int r = 0; r < 4; ++r)
          if (j * 64 + nt * 16 + q * 4 + r > tg) p2[nt][r] = -1e30f;
    }

    float mx = p2[0][0];
#pragma unroll
    for (int nt = 0; nt < 4; ++nt)
#pragma unroll
      for (int r = 0; r < 4; ++r) mx = fmaxf(mx, p2[nt][r]);
    mx = fmaxf(mx, __shfl_xor(mx, 16));
    mx = fmaxf(mx, __shfl_xor(mx, 32));
    float mn = fmaxf(m, mx);
    float alpha = exp2f(m - mn);
    m = mn;

    float rs = 0.f;
    s4v Pf[4];
#pragma unroll
    for (int nt = 0; nt < 4; ++nt)
#pragma unroll
      for (int r = 0; r < 4; ++r) {
        float e = exp2f(p2[nt][r] - mn);
        rs += e;
        Pf[nt][r] = f2bf(e);
      }
    rs += __shfl_xor(rs, 16);
    rs += __shfl_xor(rs, 32);
    lsum = lsum * alpha + rs;
#pragma unroll
    for (int dt = 0; dt < 4; ++dt) O[dt] *= alpha;

    // PV: A = V^T rows (m = d), B = P (n = t, k = s in C-layout regs)
#pragma unroll
    for (int sc = 0; sc < 4; ++sc) {
      int so = ((sc * 2 + (q >> 1)) ^ lx) * 16 + (q & 1) * 8;
#pragma unroll
      for (int dt = 0; dt < 4; ++dt) {
        s4v vv = *(const s4v*)(Vl + (dt * 16 + l) * 128 + so);
        O[dt] = __builtin_amdgcn_mfma_f32_16x16x16bf16_1k(vv, Pf[sc], O[dt], 0, 0, 0);
      }
    }
    __syncthreads();  // staging of j+1 drained; all waves done with buf (j&1)
  }

  // epilogue: lane holds row t = tg, cols d = dt*16 + q*4 + r  -> float4 stores
  float inv = 1.f / lsum;
  int b = bh >> 4, h = bh & 15;
  float* ob = out + ((size_t)b * 2048 + tg) * 1024 + h * 64;
#pragma unroll
  for (int dt = 0; dt < 4; ++dt) {
    f4v val = O[dt] * inv;
    *(f4v*)(ob + dt * 16 + q * 4) = val;
  }
}

extern "C" void kernel_launch(void* const* d_in, const int* in_sizes, int n_in,
                              void* d_out, int out_size, void* d_ws, size_t ws_size,
                              hipStream_t stream) {
  const float* x = (const float*)d_in[0];     // [2,2048,1024]
  const float* W = (const float*)d_in[1];     // [1024,3072]
  const float* bias = (const float*)d_in[2];  // [3072]
  float* out = (float*)d_out;                 // [2,2048,1024]

  char* ws = (char*)d_ws;
  __hip_bfloat16* xb = (__hip_bfloat16*)ws;                    // 8,388,608 B
  __hip_bfloat16* Wt = (__hip_bfloat16*)(ws + 8388608);        // 6,291,456 B
  __hip_bfloat16* Qg = (__hip_bfloat16*)(ws + 14680064);       // 8,388,608 B
  __hip_bfloat16* Kg = (__hip_bfloat16*)(ws + 23068672);       // 8,388,608 B
  __hip_bfloat16* Vt = (__hip_bfloat16*)(ws + 31457280);       // 8,388,608 B

  k_prep<<<7168, 256, 0, stream>>>(x, W, xb, Wt);
  k_gemm<<<dim3(24, 32), 256, 0, stream>>>(xb, Wt, bias, Qg, Kg, Vt);
  k_attn<<<1024, 256, 0, stream>>>(Qg, Kg, Vt, out);
}

// Round 6
// 189.077 us; speedup vs baseline: 1.6413x; 1.0385x over previous
//
#include <hip/hip_runtime.h>
#include <hip/hip_bf16.h>

typedef __attribute__((ext_vector_type(8))) short s8v;    // 8 bf16
typedef __attribute__((ext_vector_type(4))) short s4v;    // 4 bf16
typedef __attribute__((ext_vector_type(4))) float f4v;    // 4 fp32

__device__ __forceinline__ void g2lds16(const void* g, void* l) {
  __builtin_amdgcn_global_load_lds(
      (__attribute__((address_space(1))) void*)(g),
      (__attribute__((address_space(3))) void*)(l), 16, 0, 0);
}

__device__ __forceinline__ short f2bf(float f) {
  __hip_bfloat16 h = __float2bfloat16(f);
  return *reinterpret_cast<short*>(&h);
}

// ---------------- K0: fused x->bf16 cvt  +  W transpose->bf16 ----------------
__global__ void k_prep(const float* __restrict__ x, const float* __restrict__ W,
                       __hip_bfloat16* __restrict__ xb, __hip_bfloat16* __restrict__ Wt) {
  int bx = blockIdx.x;
  if (bx < 4096) {
    int i = (bx * 256 + threadIdx.x) * 4;
    float4 v = *(const float4*)(x + i);
    __hip_bfloat16 o[4] = {__float2bfloat16(v.x), __float2bfloat16(v.y),
                           __float2bfloat16(v.z), __float2bfloat16(v.w)};
    *(uint2*)(xb + i) = *(const uint2*)(o);
  } else {
    __shared__ float tile[32][33];
    int r = bx - 4096;            // 0..3071 = 32 x 96
    int rt = r / 96;              // over 1024/32
    int ct = r - rt * 96;         // over 3072/32
    int c0 = ct * 32, r0 = rt * 32;
    int tr = threadIdx.x >> 5, tc = threadIdx.x & 31;
#pragma unroll
    for (int i = 0; i < 32; i += 8)
      tile[tr + i][tc] = W[(size_t)(r0 + tr + i) * 3072 + c0 + tc];
    __syncthreads();
#pragma unroll
    for (int i = 0; i < 32; i += 8)
      Wt[(size_t)(c0 + tr + i) * 1024 + r0 + tc] = __float2bfloat16(tile[tc][tr + i]);
  }
}

// ---------------- K1: GEMM + fused QKV scatter epilogue ----------------
// Y element (row rr, col c): flat = rr*3072 + c. With u = 3*rr + (c>>10):
//   s = u>>12, b = (u>>11)&1, t = u&2047, d = (c&1023)>>4, h = c&15.
// s=0 -> Q[b,h,t,d], s=1 -> K[b,h,t,d], s=2 -> Vt[b,h,d,t]
// Double-buffered LDS (1 barrier/iter), bank-swizzled tiles, XCD-affine tiles.
__global__ __launch_bounds__(256) void k_gemm(const __hip_bfloat16* __restrict__ A,
                                              const __hip_bfloat16* __restrict__ Bt,
                                              const float* __restrict__ bias,
                                              __hip_bfloat16* __restrict__ Q,
                                              __hip_bfloat16* __restrict__ K,
                                              __hip_bfloat16* __restrict__ Vt) {
  __shared__ __align__(16) __hip_bfloat16 As[2][128 * 32];
  __shared__ __align__(16) __hip_bfloat16 Bs[2][128 * 32];
  const int tid = threadIdx.x;
  const int lane = tid & 63, wave = tid >> 6;
  // XCD-affine mapping: 3 n-tiles pinned per XCD, m-major within XCD.
  const int bid = blockIdx.x;           // 768 blocks
  const int xcd = bid & 7;
  const int i = bid >> 3;               // 0..95
  const int n0 = (xcd * 3 + (i % 3)) * 128;
  const int m0 = (i / 3) * 128;
  const int wm = (wave & 1) * 64, wn = (wave >> 1) * 64;
  const int lrow = lane & 15;
  const int quad = lane >> 4;

  f4v acc[4][4] = {};

  auto stage = [&](int k0, int kb) {
#pragma unroll
    for (int c = 0; c < 2; ++c) {
      int e = c * 2048 + tid * 8;             // element idx in 128x32 tile
      int row = e >> 5;
      int slot = (e & 31) >> 3;               // 0..3 (8-elem slots)
      int src = k0 + ((slot ^ ((row >> 1) & 3)) << 3);
      g2lds16(A + (size_t)(m0 + row) * 1024 + src, &As[kb][e]);
      g2lds16(Bt + (size_t)(n0 + row) * 1024 + src, &Bs[kb][e]);
    }
  };

  const int swz = (quad ^ ((lrow >> 1) & 3)) * 8;  // swizzled k-slot for frag reads

  stage(0, 0);
  for (int it = 0; it < 32; ++it) {
    __syncthreads();                    // drains stage(it) (issued one iter ago)
    if (it < 31) stage((it + 1) * 32, (it + 1) & 1);
    const __hip_bfloat16* Ab = As[it & 1];
    const __hip_bfloat16* Bb = Bs[it & 1];
    s8v af[4], bfr[4];
#pragma unroll
    for (int mi = 0; mi < 4; ++mi) af[mi] = *(const s8v*)(Ab + (wm + mi * 16 + lrow) * 32 + swz);
#pragma unroll
    for (int ni = 0; ni < 4; ++ni) bfr[ni] = *(const s8v*)(Bb + (wn + ni * 16 + lrow) * 32 + swz);
#pragma unroll
    for (int mi = 0; mi < 4; ++mi)
#pragma unroll
      for (int ni = 0; ni < 4; ++ni)
        acc[mi][ni] = __builtin_amdgcn_mfma_f32_16x16x32_bf16(af[mi], bfr[ni], acc[mi][ni], 0, 0, 0);
  }

  // epilogue: per-row destination decode, d-packed 8B stores for Q/K
  const int cw = n0 + wn;            // multiple of 64 -> c10 wave-uniform
  const int c10 = cw >> 10;          // 0..2
  const int d0 = (cw & 1023) >> 4;   // multiple of 4
  const int h = lrow;
  float bv[4];
#pragma unroll
  for (int ni = 0; ni < 4; ++ni) bv[ni] = bias[cw + ni * 16 + lrow];

#pragma unroll
  for (int mi = 0; mi < 4; ++mi) {
    int rbase = m0 + wm + mi * 16 + quad * 4;
#pragma unroll
    for (int reg = 0; reg < 4; ++reg) {
      int rr = rbase + reg;
      int u = 3 * rr + c10;
      int s = u >> 12;
      int b = (u >> 11) & 1;
      int t = u & 2047;
      if (s < 2) {
        __hip_bfloat16* dst = (s == 0) ? Q : K;
        s4v pk;
#pragma unroll
        for (int ni = 0; ni < 4; ++ni) pk[ni] = f2bf(acc[mi][ni][reg] + bv[ni]);
        *(s4v*)(dst + ((size_t)(b * 16 + h) * 2048 + t) * 64 + d0) = pk;
      } else {
#pragma unroll
        for (int ni = 0; ni < 4; ++ni)
          Vt[((size_t)(b * 16 + h) * 64 + d0 + ni) * 2048 + t] =
              __float2bfloat16(acc[mi][ni][reg] + bv[ni]);
      }
    }
  }
}

// ---------------- K2: causal flash attention ----------------
// 4 waves / block, 64 Q rows (16/wave). K/V tiles staged coalesced via
// global_load_lds into a double-buffered, XOR-swizzled LDS (swizzle applied by
// permuting the *global source* per lane). One barrier per KV tile.
// S^T = MFMA(A=K, B=Q): softmax per-lane over regs + 2 shuffles; P stays in
// registers and feeds PV (O^T = V^T P^T) as the B operand of 16x16x16bf16_1k.
__global__ __launch_bounds__(256, 3) void k_attn(const __hip_bfloat16* __restrict__ Q,
                                                 const __hip_bfloat16* __restrict__ K,
                                                 const __hip_bfloat16* __restrict__ Vt,
                                                 float* __restrict__ out) {
  __shared__ __align__(16) char lds[2][16384];  // per buf: K tile 8KB | V tile 8KB

  const int tid = threadIdx.x;
  const int lane = tid & 63, w = tid >> 6;
  const int l = lane & 15, q = lane >> 4, lx = l & 7;

  const int bid = blockIdx.x;           // 1024 blocks
  const int xcd = bid & 7;
  const int idx = bid >> 3;             // 0..127
  const int bh = xcd + 8 * (idx & 3);   // 4 bh per XCD -> 2MB K+V in its L2
  const int qb = 31 - (idx >> 2);       // heavy blocks first; tiles 0..qb

  const char* Kb = (const char*)(K + (size_t)bh * 131072);
  const char* Vb = (const char*)(Vt + (size_t)bh * 131072);
  const __hip_bfloat16* Qp = Q + (size_t)bh * 131072 + (size_t)qb * 4096;

  // Q fragment (load once): B[n=t][k], t = qb*64 + w*16 + l
  s8v Qf[2];
#pragma unroll
  for (int kh = 0; kh < 2; ++kh)
    Qf[kh] = *(const s8v*)(Qp + (size_t)(w * 16 + l) * 64 + kh * 32 + q * 8);

  f4v O[4] = {};
  float m = -INFINITY, lsum = 0.f;
  const float c1 = 0.125f * 1.44269504088896f;  // scale * log2(e)
  const int tg = qb * 64 + w * 16 + l;          // this lane's global Q row

  auto stage = [&](int j, char* buf) {
#pragma unroll
    for (int c = 0; c < 4; ++c) {
      int chunk = w * 4 + c;            // 0..15
      int ls = chunk * 64 + lane;       // 16B-slot index
      if (chunk < 8) {                  // K tile: LDS[row][kb] = K[row][kb ^ (row&7)]
        int row = ls >> 3, kb = ls & 7;
        g2lds16(Kb + (size_t)j * 8192 + row * 128 + ((kb ^ (row & 7)) << 4),
                buf + ls * 16);
      } else {                          // V tile: LDS[d][kb] = V^T[d][kb ^ (d&7)]
        int ls2 = ls - 512;
        int d = ls2 >> 3, kb = ls2 & 7;
        g2lds16(Vb + (size_t)d * 4096 + (size_t)j * 128 + ((kb ^ (d & 7)) << 4),
                buf + 8192 + ls2 * 16);
      }
    }
  };

  stage(0, lds[0]);
  __syncthreads();

  for (int j = 0; j <= qb; ++j) {
    const char* Kl = lds[j & 1];
    const char* Vl = Kl + 8192;
    if (j < qb) stage(j + 1, lds[(j + 1) & 1]);

    // S^T: A = K rows (m = s_local), B = Q (n = t)
    f4v S[4];
#pragma unroll
    for (int nt = 0; nt < 4; ++nt) {
      const char* rowp = Kl + (nt * 16 + l) * 128;
      s8v k0 = *(const s8v*)(rowp + ((q ^ lx) << 4));
      s8v k1 = *(const s8v*)(rowp + (((4 + q) ^ lx) << 4));
      f4v z = {0.f, 0.f, 0.f, 0.f};
      z = __builtin_amdgcn_mfma_f32_16x16x32_bf16(k0, Qf[0], z, 0, 0, 0);
      z = __builtin_amdgcn_mfma_f32_16x16x32_bf16(k1, Qf[1], z, 0, 0, 0);
      S[nt] = z;
    }

    float p2[4][4];
#pragma unroll
    for (int nt = 0; nt < 4; ++nt)
#pragma unroll
      for (int r = 0; r < 4; ++r) p2[nt][r] = S[nt][r] * c1;
    if (j == qb) {
#pragma unroll
      for (int nt = 0; nt < 4; ++nt)
#pragma unroll
        for (int r = 0; r < 4; ++r)
          if (j * 64 + nt * 16 + q * 4 + r > tg) p2[nt][r] = -1e30f;
    }

    float mx = p2[0][0];
#pragma unroll
    for (int nt = 0; nt < 4; ++nt)
#pragma unroll
      for (int r = 0; r < 4; ++r) mx = fmaxf(mx, p2[nt][r]);
    mx = fmaxf(mx, __shfl_xor(mx, 16));
    mx = fmaxf(mx, __shfl_xor(mx, 32));
    float mn = fmaxf(m, mx);
    float alpha = exp2f(m - mn);
    m = mn;

    float rs = 0.f;
    s4v Pf[4];
#pragma unroll
    for (int nt = 0; nt < 4; ++nt)
#pragma unroll
      for (int r = 0; r < 4; ++r) {
        float e = exp2f(p2[nt][r] - mn);
        rs += e;
        Pf[nt][r] = f2bf(e);
      }
    rs += __shfl_xor(rs, 16);
    rs += __shfl_xor(rs, 32);
    lsum = lsum * alpha + rs;
#pragma unroll
    for (int dt = 0; dt < 4; ++dt) O[dt] *= alpha;

    // PV: A = V^T rows (m = d), B = P (n = t, k = s in C-layout regs)
#pragma unroll
    for (int sc = 0; sc < 4; ++sc) {
      int so = ((sc * 2 + (q >> 1)) ^ lx) * 16 + (q & 1) * 8;
#pragma unroll
      for (int dt = 0; dt < 4; ++dt) {
        s4v vv = *(const s4v*)(Vl + (dt * 16 + l) * 128 + so);
        O[dt] = __builtin_amdgcn_mfma_f32_16x16x16bf16_1k(vv, Pf[sc], O[dt], 0, 0, 0);
      }
    }
    __syncthreads();  // staging of j+1 drained; all waves done with buf (j&1)
  }

  // epilogue: lane holds row t = tg, cols d = dt*16 + q*4 + r  -> float4 stores
  float inv = 1.f / lsum;
  int b = bh >> 4, h = bh & 15;
  float* ob = out + ((size_t)b * 2048 + tg) * 1024 + h * 64;
#pragma unroll
  for (int dt = 0; dt < 4; ++dt) {
    f4v val = O[dt] * inv;
    *(f4v*)(ob + dt * 16 + q * 4) = val;
  }
}

extern "C" void kernel_launch(void* const* d_in, const int* in_sizes, int n_in,
                              void* d_out, int out_size, void* d_ws, size_t ws_size,
                              hipStream_t stream) {
  const float* x = (const float*)d_in[0];     // [2,2048,1024]
  const float* W = (const float*)d_in[1];     // [1024,3072]
  const float* bias = (const float*)d_in[2];  // [3072]
  float* out = (float*)d_out;                 // [2,2048,1024]

  char* ws = (char*)d_ws;
  __hip_bfloat16* xb = (__hip_bfloat16*)ws;                    // 8,388,608 B
  __hip_bfloat16* Wt = (__hip_bfloat16*)(ws + 8388608);        // 6,291,456 B
  __hip_bfloat16* Qg = (__hip_bfloat16*)(ws + 14680064);       // 8,388,608 B
  __hip_bfloat16* Kg = (__hip_bfloat16*)(ws + 23068672);       // 8,388,608 B
  __hip_bfloat16* Vt = (__hip_bfloat16*)(ws + 31457280);       // 8,388,608 B

  k_prep<<<7168, 256, 0, stream>>>(x, W, xb, Wt);
  k_gemm<<<768, 256, 0, stream>>>(xb, Wt, bias, Qg, Kg, Vt);
  k_attn<<<1024, 256, 0, stream>>>(Qg, Kg, Vt, out);
}

// Round 7
// 178.703 us; speedup vs baseline: 1.7366x; 1.0580x over previous
//
#include <hip/hip_runtime.h>
#include <hip/hip_bf16.h>

typedef __attribute__((ext_vector_type(8))) short s8v;    // 8 bf16
typedef __attribute__((ext_vector_type(4))) short s4v;    // 4 bf16
typedef __attribute__((ext_vector_type(4))) float f4v;    // 4 fp32

__device__ __forceinline__ void g2lds16(const void* g, void* l) {
  __builtin_amdgcn_global_load_lds(
      (__attribute__((address_space(1))) void*)(g),
      (__attribute__((address_space(3))) void*)(l), 16, 0, 0);
}

__device__ __forceinline__ short f2bf(float f) {
  __hip_bfloat16 h = __float2bfloat16(f);
  return *reinterpret_cast<short*>(&h);
}

// ---------------- K0: fused x->bf16 cvt  +  W transpose->bf16 ----------------
__global__ void k_prep(const float* __restrict__ x, const float* __restrict__ W,
                       __hip_bfloat16* __restrict__ xb, __hip_bfloat16* __restrict__ Wt) {
  int bx = blockIdx.x;
  if (bx < 4096) {
    int i = (bx * 256 + threadIdx.x) * 4;
    float4 v = *(const float4*)(x + i);
    __hip_bfloat16 o[4] = {__float2bfloat16(v.x), __float2bfloat16(v.y),
                           __float2bfloat16(v.z), __float2bfloat16(v.w)};
    *(uint2*)(xb + i) = *(const uint2*)(o);
  } else {
    __shared__ float tile[32][33];
    int r = bx - 4096;            // 0..3071 = 32 x 96
    int rt = r / 96;              // over 1024/32
    int ct = r - rt * 96;         // over 3072/32
    int c0 = ct * 32, r0 = rt * 32;
    int tr = threadIdx.x >> 5, tc = threadIdx.x & 31;
#pragma unroll
    for (int i = 0; i < 32; i += 8)
      tile[tr + i][tc] = W[(size_t)(r0 + tr + i) * 3072 + c0 + tc];
    __syncthreads();
#pragma unroll
    for (int i = 0; i < 32; i += 8)
      Wt[(size_t)(c0 + tr + i) * 1024 + r0 + tc] = __float2bfloat16(tile[tc][tr + i]);
  }
}

// ---------------- K1: GEMM + fused QKV scatter epilogue ----------------
// Y element (row rr, col c): flat = rr*3072 + c. With u = 3*rr + (c>>10):
//   s = u>>12, b = (u>>11)&1, t = u&2047, d = (c&1023)>>4, h = c&15.
// s=0 -> Q[b,h,t,d], s=1 -> K[b,h,t,d], s=2 -> Vt[b,h,d,t]
// Grid (24,32) n-fastest: the 3 c10-writer blocks of each output line land on
// the SAME XCD (bids differ by 8) -> partial-line writes merge in one L2.
// Double-buffered LDS (1 barrier/iter) + bank-swizzled tiles.
__global__ __launch_bounds__(256) void k_gemm(const __hip_bfloat16* __restrict__ A,
                                              const __hip_bfloat16* __restrict__ Bt,
                                              const float* __restrict__ bias,
                                              __hip_bfloat16* __restrict__ Q,
                                              __hip_bfloat16* __restrict__ K,
                                              __hip_bfloat16* __restrict__ Vt) {
  __shared__ __align__(16) __hip_bfloat16 As[2][128 * 32];
  __shared__ __align__(16) __hip_bfloat16 Bs[2][128 * 32];
  const int tid = threadIdx.x;
  const int lane = tid & 63, wave = tid >> 6;
  const int m0 = blockIdx.y * 128, n0 = blockIdx.x * 128;
  const int wm = (wave & 1) * 64, wn = (wave >> 1) * 64;
  const int lrow = lane & 15;
  const int quad = lane >> 4;

  f4v acc[4][4] = {};

  auto stage = [&](int k0, int kb) {
#pragma unroll
    for (int c = 0; c < 2; ++c) {
      int e = c * 2048 + tid * 8;             // element idx in 128x32 tile
      int row = e >> 5;
      int slot = (e & 31) >> 3;               // 0..3 (8-elem slots)
      int src = k0 + ((slot ^ ((row >> 1) & 3)) << 3);
      g2lds16(A + (size_t)(m0 + row) * 1024 + src, &As[kb][e]);
      g2lds16(Bt + (size_t)(n0 + row) * 1024 + src, &Bs[kb][e]);
    }
  };

  const int swz = (quad ^ ((lrow >> 1) & 3)) * 8;  // swizzled k-slot for frag reads

  stage(0, 0);
  for (int it = 0; it < 32; ++it) {
    __syncthreads();                    // drains stage(it) (issued one iter ago)
    if (it < 31) stage((it + 1) * 32, (it + 1) & 1);
    const __hip_bfloat16* Ab = As[it & 1];
    const __hip_bfloat16* Bb = Bs[it & 1];
    s8v af[4], bfr[4];
#pragma unroll
    for (int mi = 0; mi < 4; ++mi) af[mi] = *(const s8v*)(Ab + (wm + mi * 16 + lrow) * 32 + swz);
#pragma unroll
    for (int ni = 0; ni < 4; ++ni) bfr[ni] = *(const s8v*)(Bb + (wn + ni * 16 + lrow) * 32 + swz);
#pragma unroll
    for (int mi = 0; mi < 4; ++mi)
#pragma unroll
      for (int ni = 0; ni < 4; ++ni)
        acc[mi][ni] = __builtin_amdgcn_mfma_f32_16x16x32_bf16(af[mi], bfr[ni], acc[mi][ni], 0, 0, 0);
  }

  // epilogue: per-row destination decode, d-packed 8B stores for Q/K
  const int cw = n0 + wn;            // multiple of 64 -> c10 wave-uniform
  const int c10 = cw >> 10;          // 0..2
  const int d0 = (cw & 1023) >> 4;   // multiple of 4
  const int h = lrow;
  float bv[4];
#pragma unroll
  for (int ni = 0; ni < 4; ++ni) bv[ni] = bias[cw + ni * 16 + lrow];

#pragma unroll
  for (int mi = 0; mi < 4; ++mi) {
    int rbase = m0 + wm + mi * 16 + quad * 4;
#pragma unroll
    for (int reg = 0; reg < 4; ++reg) {
      int rr = rbase + reg;
      int u = 3 * rr + c10;
      int s = u >> 12;
      int b = (u >> 11) & 1;
      int t = u & 2047;
      if (s < 2) {
        __hip_bfloat16* dst = (s == 0) ? Q : K;
        s4v pk;
#pragma unroll
        for (int ni = 0; ni < 4; ++ni) pk[ni] = f2bf(acc[mi][ni][reg] + bv[ni]);
        *(s4v*)(dst + ((size_t)(b * 16 + h) * 2048 + t) * 64 + d0) = pk;
      } else {
#pragma unroll
        for (int ni = 0; ni < 4; ++ni)
          Vt[((size_t)(b * 16 + h) * 64 + d0 + ni) * 2048 + t] =
              __float2bfloat16(acc[mi][ni][reg] + bv[ni]);
      }
    }
  }
}

// ---------------- K2: causal flash attention ----------------
// 4 waves / block, 64 Q rows (16/wave). K/V tiles staged coalesced via
// global_load_lds into a double-buffered, XOR-swizzled LDS (swizzle applied by
// permuting the *global source* per lane). One barrier per KV tile.
// S^T = MFMA(A=K, B=Q): softmax per-lane over regs + 2 shuffles; P stays in
// registers and feeds PV (O^T = V^T P^T) as the B operand of 16x16x16bf16_1k.
__global__ __launch_bounds__(256, 3) void k_attn(const __hip_bfloat16* __restrict__ Q,
                                                 const __hip_bfloat16* __restrict__ K,
                                                 const __hip_bfloat16* __restrict__ Vt,
                                                 float* __restrict__ out) {
  __shared__ __align__(16) char lds[2][16384];  // per buf: K tile 8KB | V tile 8KB

  const int tid = threadIdx.x;
  const int lane = tid & 63, w = tid >> 6;
  const int l = lane & 15, q = lane >> 4, lx = l & 7;

  const int bid = blockIdx.x;           // 1024 blocks
  const int xcd = bid & 7;
  const int idx = bid >> 3;             // 0..127
  const int bh = xcd + 8 * (idx & 3);   // 4 bh per XCD -> 2MB K+V in its L2
  const int qb = 31 - (idx >> 2);       // heavy blocks first; tiles 0..qb

  const char* Kb = (const char*)(K + (size_t)bh * 131072);
  const char* Vb = (const char*)(Vt + (size_t)bh * 131072);
  const __hip_bfloat16* Qp = Q + (size_t)bh * 131072 + (size_t)qb * 4096;

  // Q fragment (load once): B[n=t][k], t = qb*64 + w*16 + l
  s8v Qf[2];
#pragma unroll
  for (int kh = 0; kh < 2; ++kh)
    Qf[kh] = *(const s8v*)(Qp + (size_t)(w * 16 + l) * 64 + kh * 32 + q * 8);

  f4v O[4] = {};
  float m = -INFINITY, lsum = 0.f;
  const float c1 = 0.125f * 1.44269504088896f;  // scale * log2(e)
  const int tg = qb * 64 + w * 16 + l;          // this lane's global Q row

  auto stage = [&](int j, char* buf) {
#pragma unroll
    for (int c = 0; c < 4; ++c) {
      int chunk = w * 4 + c;            // 0..15
      int ls = chunk * 64 + lane;       // 16B-slot index
      if (chunk < 8) {                  // K tile: LDS[row][kb] = K[row][kb ^ (row&7)]
        int row = ls >> 3, kb = ls & 7;
        g2lds16(Kb + (size_t)j * 8192 + row * 128 + ((kb ^ (row & 7)) << 4),
                buf + ls * 16);
      } else {                          // V tile: LDS[d][kb] = V^T[d][kb ^ (d&7)]
        int ls2 = ls - 512;
        int d = ls2 >> 3, kb = ls2 & 7;
        g2lds16(Vb + (size_t)d * 4096 + (size_t)j * 128 + ((kb ^ (d & 7)) << 4),
                buf + 8192 + ls2 * 16);
      }
    }
  };

  stage(0, lds[0]);
  __syncthreads();

  for (int j = 0; j <= qb; ++j) {
    const char* Kl = lds[j & 1];
    const char* Vl = Kl + 8192;
    if (j < qb) stage(j + 1, lds[(j + 1) & 1]);

    // S^T: A = K rows (m = s_local), B = Q (n = t)
    f4v S[4];
#pragma unroll
    for (int nt = 0; nt < 4; ++nt) {
      const char* rowp = Kl + (nt * 16 + l) * 128;
      s8v k0 = *(const s8v*)(rowp + ((q ^ lx) << 4));
      s8v k1 = *(const s8v*)(rowp + (((4 + q) ^ lx) << 4));
      f4v z = {0.f, 0.f, 0.f, 0.f};
      z = __builtin_amdgcn_mfma_f32_16x16x32_bf16(k0, Qf[0], z, 0, 0, 0);
      z = __builtin_amdgcn_mfma_f32_16x16x32_bf16(k1, Qf[1], z, 0, 0, 0);
      S[nt] = z;
    }

    float p2[4][4];
#pragma unroll
    for (int nt = 0; nt < 4; ++nt)
#pragma unroll
      for (int r = 0; r < 4; ++r) p2[nt][r] = S[nt][r] * c1;
    if (j == qb) {
#pragma unroll
      for (int nt = 0; nt < 4; ++nt)
#pragma unroll
        for (int r = 0; r < 4; ++r)
          if (j * 64 + nt * 16 + q * 4 + r > tg) p2[nt][r] = -1e30f;
    }

    float mx = p2[0][0];
#pragma unroll
    for (int nt = 0; nt < 4; ++nt)
#pragma unroll
      for (int r = 0; r < 4; ++r) mx = fmaxf(mx, p2[nt][r]);
    mx = fmaxf(mx, __shfl_xor(mx, 16));
    mx = fmaxf(mx, __shfl_xor(mx, 32));
    float mn = fmaxf(m, mx);
    float alpha = exp2f(m - mn);
    m = mn;

    float rs = 0.f;
    s4v Pf[4];
#pragma unroll
    for (int nt = 0; nt < 4; ++nt)
#pragma unroll
      for (int r = 0; r < 4; ++r) {
        float e = exp2f(p2[nt][r] - mn);
        rs += e;
        Pf[nt][r] = f2bf(e);
      }
    rs += __shfl_xor(rs, 16);
    rs += __shfl_xor(rs, 32);
    lsum = lsum * alpha + rs;
#pragma unroll
    for (int dt = 0; dt < 4; ++dt) O[dt] *= alpha;

    // PV: A = V^T rows (m = d), B = P (n = t, k = s in C-layout regs)
#pragma unroll
    for (int sc = 0; sc < 4; ++sc) {
      int so = ((sc * 2 + (q >> 1)) ^ lx) * 16 + (q & 1) * 8;
#pragma unroll
      for (int dt = 0; dt < 4; ++dt) {
        s4v vv = *(const s4v*)(Vl + (dt * 16 + l) * 128 + so);
        O[dt] = __builtin_amdgcn_mfma_f32_16x16x16bf16_1k(vv, Pf[sc], O[dt], 0, 0, 0);
      }
    }
    __syncthreads();  // staging of j+1 drained; all waves done with buf (j&1)
  }

  // epilogue: lane holds row t = tg, cols d = dt*16 + q*4 + r  -> float4 stores
  float inv = 1.f / lsum;
  int b = bh >> 4, h = bh & 15;
  float* ob = out + ((size_t)b * 2048 + tg) * 1024 + h * 64;
#pragma unroll
  for (int dt = 0; dt < 4; ++dt) {
    f4v val = O[dt] * inv;
    *(f4v*)(ob + dt * 16 + q * 4) = val;
  }
}

extern "C" void kernel_launch(void* const* d_in, const int* in_sizes, int n_in,
                              void* d_out, int out_size, void* d_ws, size_t ws_size,
                              hipStream_t stream) {
  const float* x = (const float*)d_in[0];     // [2,2048,1024]
  const float* W = (const float*)d_in[1];     // [1024,3072]
  const float* bias = (const float*)d_in[2];  // [3072]
  float* out = (float*)d_out;                 // [2,2048,1024]

  char* ws = (char*)d_ws;
  __hip_bfloat16* xb = (__hip_bfloat16*)ws;                    // 8,388,608 B
  __hip_bfloat16* Wt = (__hip_bfloat16*)(ws + 8388608);        // 6,291,456 B
  __hip_bfloat16* Qg = (__hip_bfloat16*)(ws + 14680064);       // 8,388,608 B
  __hip_bfloat16* Kg = (__hip_bfloat16*)(ws + 23068672);       // 8,388,608 B
  __hip_bfloat16* Vt = (__hip_bfloat16*)(ws + 31457280);       // 8,388,608 B

  k_prep<<<7168, 256, 0, stream>>>(x, W, xb, Wt);
  k_gemm<<<dim3(24, 32), 256, 0, stream>>>(xb, Wt, bias, Qg, Kg, Vt);
  k_attn<<<1024, 256, 0, stream>>>(Qg, Kg, Vt, out);
}